// Round 13
// baseline (659.893 us; speedup 1.0000x reference)
//
#include <hip/hip_runtime.h>

namespace {

constexpr int B_TOT  = 2048;
constexpr int T_SEQ  = 66;
constexpr int IN_DIM = 9;
constexpr int H      = 100;
constexpr int N      = 128;
constexpr int D      = 20;
constexpr int G      = 4;      // sequences per block
constexpr int NTHR   = 512;    // 8 waves, 2 blocks/CU (proven no-spill config)
constexpr float CLIPV = 20.0f;

constexpr int NCT_SM  = 25;
constexpr int WS_BIG_SLOTS = 32 * 4 * 64;        // 8192
constexpr int WS_SM_OFF_U16 = WS_BIG_SLOTS * 8;  // 65536 ushorts
constexpr int WS_SM_SLOTS = NCT_SM * 64;         // 1600

constexpr int MT_ROW = 140;             // M transposed [d][n]: bank shift 12/row (was 4)
constexpr int MSKT   = D * MT_ROW + 4;  // 2804 per-g stride

constexpr int HA_STRIDE = 144;          // ushorts/row: bank shift 8/row (2-way max)
constexpr int HA_LO     = 4 * HA_STRIDE;       // 576
constexpr int HA_TOT    = 8 * HA_STRIDE;       // 1152
constexpr int SA_STRIDE = 48;           // bank shift 24/row (2-way max)
constexpr int SA_TOT    = 4 * SA_STRIDE;       // 192
constexpr int W_ROW = 132;

// ---- LDS layout (float words) ----
constexpr int OFF_M    = 0;                    // [4][2804] = 11216
constexpr int OFF_GT   = OFF_M + G * MSKT;     // [512][4]
constexpr int OFF_C    = OFF_GT + 2048;        // [100][4]
constexpr int OFF_HA   = OFF_C + 400;          // ushort[2][4][144]
constexpr int OFF_SA   = OFF_HA + HA_TOT / 2;  // ushort[4][48]
constexpr int OFF_BIAS = OFF_SA + SA_TOT / 2;  // [512]
constexpr int OFF_R    = OFF_BIAS + 512;       // [20][4]
constexpr int OFF_KV   = OFF_R + 80;           // [8][20]
constexpr int OFF_SC   = OFF_KV + 160;         // [8][8]
constexpr int OFF_EA   = OFF_SC + 64;          // [4][40]
constexpr int OFF_MN   = OFF_EA + 160;         // [4][128]
constexpr int OFF_W    = OFF_MN + 512;         // [8][132]
constexpr int OFF_WO2  = OFF_W + 8 * W_ROW;    // [20][8]
constexpr int OFF_OUT  = OFF_WO2 + 160;        // [4*36*8]
constexpr int SMEM_FLOATS = OFF_OUT + 1152;    // 18192
constexpr int SMEM_BYTES  = SMEM_FLOATS * 4;   // 72768 -> 2 blocks/CU

typedef __attribute__((ext_vector_type(8))) short bf16x8;
typedef __attribute__((ext_vector_type(4))) float f32x4;

__device__ __forceinline__ float fexp2(float x) { return __builtin_amdgcn_exp2f(x); }
__device__ __forceinline__ float flog2(float x) { return __builtin_amdgcn_logf(x); }
__device__ __forceinline__ float frcp(float x)  { return __builtin_amdgcn_rcpf(x); }
__device__ __forceinline__ float fexp(float x)  { return fexp2(x * 1.4426950408889634f); }
__device__ __forceinline__ float fsig(float x)  { return frcp(1.f + fexp2(-1.4426950408889634f * x)); }
__device__ __forceinline__ float ftanh(float x) { return 1.f - 2.f * frcp(1.f + fexp2(2.8853900817779268f * x)); }
__device__ __forceinline__ float fsoftplus(float x) { return log1pf(fexp(x)); }

__device__ __forceinline__ unsigned short f2bf(float x) {
  unsigned u = __float_as_uint(x);
  u = (u + 0x7FFFu + ((u >> 16) & 1u)) >> 16;
  return (unsigned short)u;
}
__device__ __forceinline__ float bf2f(unsigned short h) {
  return __uint_as_float(((unsigned)h) << 16);
}

template <int C>
__device__ __forceinline__ float dpp_add(float x) {
  return x + __int_as_float(__builtin_amdgcn_mov_dpp(__float_as_int(x), C, 0xF, 0xF, true));
}
__device__ __forceinline__ float qred(float x) { return dpp_add<0x4E>(dpp_add<0xB1>(x)); }

__device__ __forceinline__ void wred_max2(float& a, float& b) {
#pragma unroll
  for (int off = 32; off; off >>= 1) {
    a = fmaxf(a, __shfl_xor(a, off, 64));
    b = fmaxf(b, __shfl_xor(b, off, 64));
  }
}
__device__ __forceinline__ void wred_sum2(float& a, float& b) {
#pragma unroll
  for (int off = 32; off; off >>= 1) {
    a += __shfl_xor(a, off, 64);
    b += __shfl_xor(b, off, 64);
  }
}

// ---- setup: pre-swizzle weights into MFMA B-fragment layout (bf16) ----
__global__ void setup_kernel(unsigned short* __restrict__ ws,
                             const float* __restrict__ Wx, const float* __restrict__ Wh,
                             const float* __restrict__ Wp, const float* __restrict__ Wo) {
  int idx = blockIdx.x * 256 + threadIdx.x;
  if (idx < WS_BIG_SLOTS) {
    int lane = idx & 63, kt = (idx >> 6) & 3, ct = idx >> 8;
    int col = ct * 16 + (lane & 15);
    int k0 = kt * 32 + ((lane >> 4) << 3);
    unsigned short v[8];
#pragma unroll
    for (int j = 0; j < 8; ++j) {
      int k = k0 + j;
      float f = 0.f;
      if (k < 100) {
        if (col < 400) f = Wh[k * 400 + col];
        else if (col < 492) f = Wp[k * 92 + (col - 400)];
        else if (col < 500) f = Wo[k * 8 + (col - 492)];
      }
      v[j] = f2bf(f);
    }
    uint4 pk;
    pk.x = (unsigned)v[0] | ((unsigned)v[1] << 16);
    pk.y = (unsigned)v[2] | ((unsigned)v[3] << 16);
    pk.z = (unsigned)v[4] | ((unsigned)v[5] << 16);
    pk.w = (unsigned)v[6] | ((unsigned)v[7] << 16);
    *(uint4*)(ws + (size_t)idx * 8) = pk;
  } else if (idx < WS_BIG_SLOTS + WS_SM_SLOTS) {
    int s = idx - WS_BIG_SLOTS;
    int lane = s & 63, ct = s >> 6;
    int col = ct * 16 + (lane & 15);
    int k0 = (lane >> 4) << 3;
    unsigned short v[8];
#pragma unroll
    for (int j = 0; j < 8; ++j) {
      int k = k0 + j;
      float f = (k < 29) ? Wx[k * 400 + col] : 0.f;
      v[j] = f2bf(f);
    }
    uint4 pk;
    pk.x = (unsigned)v[0] | ((unsigned)v[1] << 16);
    pk.y = (unsigned)v[2] | ((unsigned)v[3] << 16);
    pk.z = (unsigned)v[4] | ((unsigned)v[5] << 16);
    pk.w = (unsigned)v[6] | ((unsigned)v[7] << 16);
    *(uint4*)(ws + (size_t)(WS_SM_OFF_U16 + (size_t)s * 8)) = pk;
  }
}

__global__ __launch_bounds__(NTHR, 4) void ntm_kernel(
    const float* __restrict__ inputs, const unsigned short* __restrict__ wsu,
    const float* __restrict__ b_lstm, const float* __restrict__ b_params,
    const float* __restrict__ b_out, const float* __restrict__ W_out,
    const int* __restrict__ seqp, float* __restrict__ outp) {
  extern __shared__ float sm[];
  const int tid = threadIdx.x;
  const int lane = tid & 63;
  const int wv = tid >> 6;
  const int b0 = blockIdx.x * G;
  const int tlim = seqp[0] + 1;
  const int TO = T_SEQ - tlim;
  const bool buffered = (TO <= 36);
  unsigned short* hAu = (unsigned short*)(sm + OFF_HA);
  unsigned short* sAu = (unsigned short*)(sm + OFF_SA);
  const bf16x8* wsBig = (const bf16x8*)wsu;
  const bf16x8* wsSm  = (const bf16x8*)(wsu + WS_SM_OFF_U16);

  // ---------------- init ----------------
  for (int i = tid; i < G * MSKT; i += NTHR) sm[OFF_M + i] = 1e-6f;
  for (int i = tid; i < 2048; i += NTHR) sm[OFF_GT + i] = 0.f;
  for (int i = tid; i < 400; i += NTHR) sm[OFF_C + i] = 0.f;
  for (int i = tid; i < HA_TOT; i += NTHR) hAu[i] = 0;
  for (int i = tid; i < SA_TOT; i += NTHR) sAu[i] = 0;
  if (tid < 512) {
    float v = 0.f;
    if (tid < 400) v = b_lstm[tid];
    else if (tid < 492) v = b_params[tid - 400];
    else if (tid < 500) v = b_out[tid - 492];
    sm[OFF_BIAS + tid] = v;
  }
  for (int i = tid; i < 80; i += NTHR) sm[OFF_R + i] = 0.f;
  for (int i = tid; i < 512; i += NTHR) sm[OFF_MN + i] = 4.47213595e-6f;
  for (int i = tid; i < 8 * W_ROW; i += NTHR)
    sm[OFF_W + i] = ((i % W_ROW) == 0) ? 1.f : 0.f;
  for (int i = tid; i < 160; i += NTHR) sm[OFF_WO2 + i] = W_out[800 + i];
  for (int i = tid; i < 1152; i += NTHR) sm[OFF_OUT + i] = 0.f;
  if (tid >= 448 && tid < 484) {  // x(0)
    int p = tid - 448, g = p / 9, k = p - g * 9;
    sAu[g * SA_STRIDE + k] = f2bf(inputs[(size_t)(b0 + g) * T_SEQ * IN_DIM + k]);
  }
  __syncthreads();

  const int arow = lane & 3;
  const int akoff = (lane >> 4) << 3;

  // ---- prologue: gates(0) = bias + [x(0), 0] @ Wx ----
  if (wv < 7) {
    bf16x8 as = *(const bf16x8*)(sAu + arow * SA_STRIDE + akoff);
#pragma unroll
    for (int cti = 0; cti < 4; ++cti) {
      int ct = wv * 4 + cti;
      if (ct < NCT_SM) {
        float bv = sm[OFF_BIAS + ct * 16 + (lane & 15)];
        f32x4 a = {bv, bv, bv, bv};
        a = __builtin_amdgcn_mfma_f32_16x16x32_bf16(as, wsSm[ct * 64 + lane], a, 0, 0, 0);
        if (lane < 16) *(f32x4*)&sm[OFF_GT + (ct * 16 + lane) * 4] = a;
      }
    }
  }
  __syncthreads();

  for (int t = 0; t < T_SEQ; ++t) {
    // ---- P_A: pointwise LSTM -> h hi/lo bf16 ; x prefetch ; output(t-1) ----
    if (tid < 400) {
      int e = tid >> 2, g = tid & 3;
      float gi = sm[OFF_GT + e * 4 + g];
      float gf = sm[OFF_GT + (100 + e) * 4 + g];
      float gz = sm[OFF_GT + (200 + e) * 4 + g];
      float go = sm[OFF_GT + (300 + e) * 4 + g];
      float c = sm[OFF_C + e * 4 + g];
      float nc = fsig(gf) * c + fsig(gi) * ftanh(gz);
      float h = fsig(go) * ftanh(nc);
      sm[OFF_C + e * 4 + g] = nc;
      unsigned short hh = f2bf(h);
      unsigned short hl = f2bf(h - bf2f(hh));
      hAu[g * HA_STRIDE + e] = hh;
      hAu[HA_LO + g * HA_STRIDE + e] = hl;
    } else if (tid >= 416 && tid < 452) {
      if (t + 1 < T_SEQ) {
        int p = tid - 416, g = p / 9, k = p - g * 9;
        sAu[g * SA_STRIDE + k] =
            f2bf(inputs[((size_t)(b0 + g) * T_SEQ + (t + 1)) * IN_DIM + k]);
      }
    } else if (tid >= 456 && tid < 488) {
      int s = t - 1;
      if (s >= tlim) {
        int u = tid - 456, g = u >> 3, o = u & 7;
        float v = sm[OFF_GT + (492 + o) * 4 + g];
#pragma unroll
        for (int d = 0; d < D; ++d)
          v = fmaf(sm[OFF_R + d * 4 + g], sm[OFF_WO2 + d * 8 + o], v);
        v = fminf(fmaxf(v, -CLIPV), CLIPV);
        v = fsig(v);
        int tp = s - tlim;
        if (buffered) sm[OFF_OUT + (g * TO + tp) * 8 + o] = v;
        else outp[((size_t)(b0 + g) * TO + tp) * 8 + o] = v;
      }
    }
    __syncthreads();  // B1

    // ---- P_B: p/hout tiles only (ct 25..31), one ct per wave ----
    if (wv < 7) {
      const int ct = 25 + wv;
      float bv = sm[OFF_BIAS + ct * 16 + (lane & 15)];
      f32x4 a = {bv, bv, bv, bv};
#pragma unroll
      for (int kt = 0; kt < 4; ++kt) {
        bf16x8 ahi = *(const bf16x8*)(hAu + arow * HA_STRIDE + kt * 32 + akoff);
        bf16x8 alo = *(const bf16x8*)(hAu + HA_LO + arow * HA_STRIDE + kt * 32 + akoff);
        bf16x8 bf = wsBig[(ct * 4 + kt) * 64 + lane];
        a = __builtin_amdgcn_mfma_f32_16x16x32_bf16(ahi, bf, a, 0, 0, 0);
        a = __builtin_amdgcn_mfma_f32_16x16x32_bf16(alo, bf, a, 0, 0, 0);
      }
      if (lane < 16) {
        int col = ct * 16 + lane;
        if (col < 492) {  // p: clip
          a.x = fminf(fmaxf(a.x, -CLIPV), CLIPV);
          a.y = fminf(fmaxf(a.y, -CLIPV), CLIPV);
          a.z = fminf(fmaxf(a.z, -CLIPV), CLIPV);
          a.w = fminf(fmaxf(a.w, -CLIPV), CLIPV);
        }
        *(f32x4*)&sm[OFF_GT + col * 4] = a;
      }
    }
    __syncthreads();  // B2

    // ---- P_C: waves 0-3 dual-head addressing ; waves 4-7 gates GEMM (overlap) ----
    if (wv < 4) {
      const int g = wv, l = lane;
      if (l < 40) {
        int hd = l >= 20, j = l - 20 * hd;
        sm[OFF_KV + (2 * g + hd) * 20 + j] =
            ftanh(sm[OFF_GT + (400 + hd * 26 + j) * 4 + g]);
      } else if (l < 52) {
        int hd = (l - 40) >= 6, which = (l - 40) - 6 * hd;
        float v = sm[OFF_GT + (400 + hd * 26 + 20 + which) * 4 + g];
        float* scp = &sm[OFF_SC + (2 * g + hd) * 8];
        if (which == 0) scp[0] = fsoftplus(v);
        else if (which == 1) scp[1] = fsig(v);
        else if (which == 2) {
          float a1 = sm[OFF_GT + (400 + hd * 26 + 23) * 4 + g];
          float a2 = sm[OFF_GT + (400 + hd * 26 + 24) * 4 + g];
          float mx = fmaxf(v, fmaxf(a1, a2));
          float e0 = fexp(v - mx), e1 = fexp(a1 - mx), e2 = fexp(a2 - mx);
          float inv = frcp(e0 + e1 + e2);
          scp[2] = e0 * inv; scp[3] = e1 * inv; scp[4] = e2 * inv;
        } else if (which == 5) {
          scp[5] = fsoftplus(v) + 1.f;
        }
      }
      asm volatile("s_waitcnt lgkmcnt(0)" ::: "memory");
      __builtin_amdgcn_sched_barrier(0);

      const float* Mg = &sm[OFF_M + g * MSKT];
      const float* kv0 = &sm[OFF_KV + (2 * g) * 20];
      const float* kv1 = &sm[OFF_KV + (2 * g + 1) * 20];
      float d00 = 0.f, d01 = 0.f, d10 = 0.f, d11 = 0.f;
      float kn0 = 0.f, kn1 = 0.f;
#pragma unroll
      for (int d = 0; d < D; ++d) {
        float k0 = kv0[d], k1 = kv1[d];
        float m0 = Mg[d * MT_ROW + l], m1 = Mg[d * MT_ROW + 64 + l];
        d00 = fmaf(k0, m0, d00); d01 = fmaf(k0, m1, d01);
        d10 = fmaf(k1, m0, d10); d11 = fmaf(k1, m1, d11);
        kn0 = fmaf(k0, k0, kn0); kn1 = fmaf(k1, k1, kn1);
      }
      kn0 = sqrtf(kn0); kn1 = sqrtf(kn1);
      float Mn0 = sm[OFF_MN + g * N + l];
      float Mn1 = sm[OFF_MN + g * N + 64 + l];
      const float* sc0 = &sm[OFF_SC + (2 * g) * 8];
      const float* sc1 = &sm[OFF_SC + (2 * g + 1) * 8];
      float be0 = sc0[0], be1 = sc1[0];
      float S00 = be0 * d00 * frcp(kn0 * Mn0 + 1e-8f);
      float S01 = be0 * d01 * frcp(kn0 * Mn1 + 1e-8f);
      float S10 = be1 * d10 * frcp(kn1 * Mn0 + 1e-8f);
      float S11 = be1 * d11 * frcp(kn1 * Mn1 + 1e-8f);
      float mx0 = fmaxf(S00, S01), mx1 = fmaxf(S10, S11);
      wred_max2(mx0, mx1);
      float e00 = fexp(S00 - mx0), e01 = fexp(S01 - mx0);
      float e10 = fexp(S10 - mx1), e11 = fexp(S11 - mx1);
      float sum0 = e00 + e01, sum1 = e10 + e11;
      wred_sum2(sum0, sum1);
      float si0 = frcp(sum0), si1 = frcp(sum1);
      float* wpa = &sm[OFF_W + (2 * g) * W_ROW];
      float* wpb = &sm[OFF_W + (2 * g + 1) * W_ROW];
      float gg0 = sc0[1], gg1 = sc1[1];
      float wa0 = wpa[l], wa1 = wpa[64 + l], wb0 = wpb[l], wb1 = wpb[64 + l];
      float wg00 = fmaf(gg0, e00 * si0 - wa0, wa0);
      float wg01 = fmaf(gg0, e01 * si0 - wa1, wa1);
      float wg10 = fmaf(gg1, e10 * si1 - wb0, wb0);
      float wg11 = fmaf(gg1, e11 * si1 - wb1, wb1);
      int lp = (l + 1) & 63, lm = (l + 63) & 63;
      float n00 = __shfl(wg00, lp, 64), n01 = __shfl(wg01, lp, 64);
      float p00 = __shfl(wg00, lm, 64), p01 = __shfl(wg01, lm, 64);
      float a0l0 = __shfl(wg00, 0, 64), a1l0 = __shfl(wg01, 0, 64);
      float a0l63 = __shfl(wg00, 63, 64), a1l63 = __shfl(wg01, 63, 64);
      float nxt00 = (l == 63) ? a1l0 : n00;
      float nxt01 = (l == 63) ? a0l0 : n01;
      float prv00 = (l == 0) ? a1l63 : p00;
      float prv01 = (l == 0) ? a0l63 : p01;
      float n10 = __shfl(wg10, lp, 64), n11 = __shfl(wg11, lp, 64);
      float p10 = __shfl(wg10, lm, 64), p11 = __shfl(wg11, lm, 64);
      float b0l0 = __shfl(wg10, 0, 64), b1l0 = __shfl(wg11, 0, 64);
      float b0l63 = __shfl(wg10, 63, 64), b1l63 = __shfl(wg11, 63, 64);
      float nxt10 = (l == 63) ? b1l0 : n10;
      float nxt11 = (l == 63) ? b0l0 : n11;
      float prv10 = (l == 0) ? b1l63 : p10;
      float prv11 = (l == 0) ? b0l63 : p11;
      float s00 = sc0[2], s01s = sc0[3], s02 = sc0[4], gm0 = sc0[5];
      float s10 = sc1[2], s11s = sc1[3], s12 = sc1[4], gm1 = sc1[5];
      float wt00 = fmaxf(fmaf(s00, nxt00, fmaf(s01s, wg00, s02 * prv00)), 1e-16f);
      float wt01 = fmaxf(fmaf(s00, nxt01, fmaf(s01s, wg01, s02 * prv01)), 1e-16f);
      float wt10 = fmaxf(fmaf(s10, nxt10, fmaf(s11s, wg10, s12 * prv10)), 1e-16f);
      float wt11 = fmaxf(fmaf(s10, nxt11, fmaf(s11s, wg11, s12 * prv11)), 1e-16f);
      float m0m = fmaxf(wt00, wt01), m1m = fmaxf(wt10, wt11);
      wred_max2(m0m, m1m);
      float iv0 = frcp(m0m), iv1 = frcp(m1m);
      float q00 = fexp2(gm0 * flog2(wt00 * iv0));
      float q01 = fexp2(gm0 * flog2(wt01 * iv0));
      float q10 = fexp2(gm1 * flog2(wt10 * iv1));
      float q11 = fexp2(gm1 * flog2(wt11 * iv1));
      float sq0 = q00 + q01, sq1 = q10 + q11;
      wred_sum2(sq0, sq1);
      float pi0 = frcp(sq0), pi1 = frcp(sq1);
      wpa[l] = q00 * pi0; wpa[64 + l] = q01 * pi0;
      wpb[l] = q10 * pi1; wpb[64 + l] = q11 * pi1;
    } else {
      // gates GEMM for t+1 partial: 25 tiles strided over waves 4-7
      const int wq = wv - 4;
      bf16x8 ahi[4], alo[4];
#pragma unroll
      for (int kt = 0; kt < 4; ++kt) {
        ahi[kt] = *(const bf16x8*)(hAu + arow * HA_STRIDE + kt * 32 + akoff);
        alo[kt] = *(const bf16x8*)(hAu + HA_LO + arow * HA_STRIDE + kt * 32 + akoff);
      }
#pragma unroll
      for (int cti = 0; cti < 7; ++cti) {
        int ct = wq + cti * 4;
        if (ct < NCT_SM) {
          float bv = sm[OFF_BIAS + ct * 16 + (lane & 15)];
          f32x4 a = {bv, bv, bv, bv};
#pragma unroll
          for (int kt = 0; kt < 4; ++kt) {
            bf16x8 bf = wsBig[(ct * 4 + kt) * 64 + lane];
            a = __builtin_amdgcn_mfma_f32_16x16x32_bf16(ahi[kt], bf, a, 0, 0, 0);
            a = __builtin_amdgcn_mfma_f32_16x16x32_bf16(alo[kt], bf, a, 0, 0, 0);
          }
          if (lane < 16) *(f32x4*)&sm[OFF_GT + (ct * 16 + lane) * 4] = a;
        }
      }
    }
    __syncthreads();  // B3

    // ---- P_D: r = w_r @ M (float4) ; e/a activations ; wS0 prefetch ----
    bf16x8 wS0;
    if (wv < 4) wS0 = wsSm[wv * 64 + lane];
    if (tid < 320) {
      int pr = tid >> 2, nq = tid & 3;
      int g = pr / 20, d = pr - g * 20;
      const float* wr = &sm[OFF_W + (2 * g) * W_ROW];
      const float* Md = &sm[OFF_M + g * MSKT + d * MT_ROW];
      float s = 0.f;
#pragma unroll
      for (int i = 0; i < 8; ++i) {
        int n = nq * 4 + i * 16;
        float4 w4 = *(const float4*)(wr + n);
        float4 m4 = *(const float4*)(Md + n);
        s = fmaf(w4.x, m4.x, fmaf(w4.y, m4.y, fmaf(w4.z, m4.z, fmaf(w4.w, m4.w, s))));
      }
      s = qred(s);
      if (nq == 0) {
        sm[OFF_R + d * 4 + g] = s;
        sAu[g * SA_STRIDE + 9 + d] = f2bf(s);
      }
    } else if (tid < 480) {
      int p = tid - 320, g = p / 40, j = p - g * 40;
      float v = sm[OFF_GT + (452 + j) * 4 + g];
      sm[OFF_EA + g * 40 + j] = (j < 20) ? fsig(v) : ftanh(v);
    }
    __syncthreads();  // B4

    // ---- P_E: small GEMM += gates (waves 0-3, 25 ct) ;
    //          M update + norm (waves 4-7, float4 n-blocks) ----
    if (wv < 4) {
      bf16x8 as = *(const bf16x8*)(sAu + arow * SA_STRIDE + akoff);
#pragma unroll
      for (int i = 0; i < 7; ++i) {
        int ct = wv + 4 * i;
        if (ct < NCT_SM) {
          bf16x8 bs = (i == 0) ? wS0 : wsSm[ct * 64 + lane];
          f32x4 c = *(const f32x4*)&sm[OFF_GT + (ct * 16 + (lane & 15)) * 4];
          c = __builtin_amdgcn_mfma_f32_16x16x32_bf16(as, bs, c, 0, 0, 0);
          if (lane < 16) *(f32x4*)&sm[OFF_GT + (ct * 16 + lane) * 4] = c;
        }
      }
    } else {
      int slot = tid - 256;           // 0..255
      int g = slot >> 6;              // one g per wave
      int rest = slot & 63;
      int n4 = (rest >> 1) << 2;      // n base (0,4,...,124)
      int dh = rest & 1;              // d half
      const float* ep = &sm[OFF_EA + g * 40];
      const float* ap = ep + 20;
      float* Mg = &sm[OFF_M + g * MSKT];
      float4 ww4 = *(const float4*)&sm[OFF_W + (2 * g + 1) * W_ROW + n4];
      float4 nrm = {0.f, 0.f, 0.f, 0.f};
#pragma unroll
      for (int dd = 0; dd < 10; ++dd) {
        int d = dh * 10 + dd;
        float ed = ep[d], ad = ap[d];
        float4 m4 = *(const float4*)(Mg + d * MT_ROW + n4);
        m4.x = fmaf(ww4.x, fmaf(-ed, m4.x, ad), m4.x);
        m4.y = fmaf(ww4.y, fmaf(-ed, m4.y, ad), m4.y);
        m4.z = fmaf(ww4.z, fmaf(-ed, m4.z, ad), m4.z);
        m4.w = fmaf(ww4.w, fmaf(-ed, m4.w, ad), m4.w);
        *(float4*)(Mg + d * MT_ROW + n4) = m4;
        nrm.x = fmaf(m4.x, m4.x, nrm.x);
        nrm.y = fmaf(m4.y, m4.y, nrm.y);
        nrm.z = fmaf(m4.z, m4.z, nrm.z);
        nrm.w = fmaf(m4.w, m4.w, nrm.w);
      }
      // combine the two d-halves (lanes l, l^1) and write norms
      nrm.x = dpp_add<0xB1>(nrm.x);
      nrm.y = dpp_add<0xB1>(nrm.y);
      nrm.z = dpp_add<0xB1>(nrm.z);
      nrm.w = dpp_add<0xB1>(nrm.w);
      if (dh == 0) {
        float4 r4;
        r4.x = sqrtf(nrm.x); r4.y = sqrtf(nrm.y);
        r4.z = sqrtf(nrm.z); r4.w = sqrtf(nrm.w);
        *(float4*)&sm[OFF_MN + g * N + n4] = r4;
      }
    }
    __syncthreads();  // B5
  }

  // ---- epilogue: output for t = T_SEQ-1, then flush ----
  if (tid < 32) {
    int s = T_SEQ - 1;
    if (s >= tlim) {
      int g = tid >> 3, o = tid & 7;
      float v = sm[OFF_GT + (492 + o) * 4 + g];
#pragma unroll
      for (int d = 0; d < D; ++d)
        v = fmaf(sm[OFF_R + d * 4 + g], sm[OFF_WO2 + d * 8 + o], v);
      v = fminf(fmaxf(v, -CLIPV), CLIPV);
      v = fsig(v);
      int tp = s - tlim;
      if (buffered) sm[OFF_OUT + (g * TO + tp) * 8 + o] = v;
      else outp[((size_t)(b0 + g) * TO + tp) * 8 + o] = v;
    }
  }
  __syncthreads();
  if (buffered) {
    const int total = G * TO * 8;
    for (int i = tid * 4; i < total; i += NTHR * 4) {
      float4 v = *(const float4*)&sm[OFF_OUT + i];
      *(float4*)&outp[(size_t)blockIdx.x * total + i] = v;
    }
  }
}

}  // namespace

extern "C" void kernel_launch(void* const* d_in, const int* in_sizes, int n_in,
                              void* d_out, int out_size, void* d_ws, size_t ws_size,
                              hipStream_t stream) {
  (void)in_sizes; (void)n_in; (void)out_size; (void)ws_size;
  const float* inputs   = (const float*)d_in[0];
  const float* Wx       = (const float*)d_in[1];
  const float* Wh       = (const float*)d_in[2];
  const float* b_lstm   = (const float*)d_in[3];
  const float* W_params = (const float*)d_in[4];
  const float* b_params = (const float*)d_in[5];
  const float* W_out    = (const float*)d_in[6];
  const float* b_out    = (const float*)d_in[7];
  const int*   seqp     = (const int*)d_in[8];
  float* out = (float*)d_out;
  unsigned short* wsu = (unsigned short*)d_ws;

  constexpr int SETUP_N = WS_BIG_SLOTS + WS_SM_SLOTS;  // 9792
  setup_kernel<<<(SETUP_N + 255) / 256, 256, 0, stream>>>(wsu, Wx, Wh, W_params,
                                                          W_out);

  hipFuncSetAttribute((const void*)ntm_kernel,
                      hipFuncAttributeMaxDynamicSharedMemorySize, SMEM_BYTES);
  ntm_kernel<<<B_TOT / G, NTHR, SMEM_BYTES, stream>>>(
      inputs, wsu, b_lstm, b_params, b_out, W_out, seqp, out);
}

// Round 14
// 558.829 us; speedup vs baseline: 1.1808x; 1.1808x over previous
//
#include <hip/hip_runtime.h>

namespace {

constexpr int B_TOT  = 2048;
constexpr int T_SEQ  = 66;
constexpr int IN_DIM = 9;
constexpr int H      = 100;
constexpr int N      = 128;
constexpr int D      = 20;
constexpr int G      = 4;      // sequences per block
constexpr int NTHR   = 512;    // 8 waves, 2 blocks/CU (proven no-spill config)
constexpr float CLIPV = 20.0f;

constexpr int NCT_SM  = 25;
constexpr int WS_BIG_SLOTS = 32 * 4 * 64;        // 8192
constexpr int WS_SM_OFF_U16 = WS_BIG_SLOTS * 8;  // 65536 ushorts
constexpr int WS_SM_SLOTS = NCT_SM * 64;         // 1600

constexpr int MT_ROW = 132;             // M transposed [d][n], padded
constexpr int MSKT   = D * MT_ROW + 4;  // 2644 per-g stride

// A-frag rows: stride 160 ush = 80 words == 16 (mod 32) -> 16 distinct
// ds_read_b128 addrs hit all 8 bank-groups exactly 2x (2-way = free, m136)
constexpr int HA_STRIDE = 160;
constexpr int HA_LO     = 4 * HA_STRIDE;       // 640
constexpr int HA_TOT    = 8 * HA_STRIDE;       // 1280
constexpr int SA_STRIDE = 32;           // 16 words == 16 (mod 32), same property
constexpr int SA_TOT    = 4 * SA_STRIDE;       // 128
constexpr int W_ROW = 132;

// ---- LDS layout (float words) ----
constexpr int OFF_M    = 0;                    // [4][20][132](+4)
constexpr int OFF_GT   = OFF_M + G * MSKT;     // [512][4]
constexpr int OFF_C    = OFF_GT + 2048;        // [100][4]
constexpr int OFF_HA   = OFF_C + 400;          // ushort[2][4][160]
constexpr int OFF_SA   = OFF_HA + HA_TOT / 2;  // ushort[4][32]
constexpr int OFF_BIAS = OFF_SA + SA_TOT / 2;  // [512]
constexpr int OFF_R    = OFF_BIAS + 512;       // [20][4]
constexpr int OFF_KV   = OFF_R + 80;           // [8][20]
constexpr int OFF_SC   = OFF_KV + 160;         // [8][8]
constexpr int OFF_EA   = OFF_SC + 64;          // [4][40]
constexpr int OFF_W    = OFF_EA + 160;         // [8][132]
constexpr int OFF_WO2  = OFF_W + 8 * W_ROW;    // [20][8]
constexpr int OFF_OUT  = OFF_WO2 + 160;        // [4*36*8]
constexpr int SMEM_FLOATS = OFF_OUT + 1152;
constexpr int SMEM_BYTES  = SMEM_FLOATS * 4;   // ~68.3 KB -> 2 blocks/CU

typedef __attribute__((ext_vector_type(8))) short bf16x8;
typedef __attribute__((ext_vector_type(4))) float f32x4;

__device__ __forceinline__ float fexp2(float x) { return __builtin_amdgcn_exp2f(x); }
__device__ __forceinline__ float flog2(float x) { return __builtin_amdgcn_logf(x); }
__device__ __forceinline__ float frcp(float x)  { return __builtin_amdgcn_rcpf(x); }
__device__ __forceinline__ float fexp(float x)  { return fexp2(x * 1.4426950408889634f); }
__device__ __forceinline__ float fsig(float x)  { return frcp(1.f + fexp2(-1.4426950408889634f * x)); }
__device__ __forceinline__ float ftanh(float x) { return 1.f - 2.f * frcp(1.f + fexp2(2.8853900817779268f * x)); }
__device__ __forceinline__ float fsoftplus(float x) { return log1pf(fexp(x)); }

__device__ __forceinline__ unsigned short f2bf(float x) {
  unsigned u = __float_as_uint(x);
  u = (u + 0x7FFFu + ((u >> 16) & 1u)) >> 16;
  return (unsigned short)u;
}
__device__ __forceinline__ float bf2f(unsigned short h) {
  return __uint_as_float(((unsigned)h) << 16);
}

template <int C>
__device__ __forceinline__ float dpp_add(float x) {
  return x + __int_as_float(__builtin_amdgcn_mov_dpp(__float_as_int(x), C, 0xF, 0xF, true));
}
__device__ __forceinline__ float qred(float x) { return dpp_add<0x4E>(dpp_add<0xB1>(x)); }

__device__ __forceinline__ void wred_max2(float& a, float& b) {
#pragma unroll
  for (int off = 32; off; off >>= 1) {
    a = fmaxf(a, __shfl_xor(a, off, 64));
    b = fmaxf(b, __shfl_xor(b, off, 64));
  }
}
__device__ __forceinline__ void wred_sum2(float& a, float& b) {
#pragma unroll
  for (int off = 32; off; off >>= 1) {
    a += __shfl_xor(a, off, 64);
    b += __shfl_xor(b, off, 64);
  }
}

// ---- setup: pre-swizzle weights into MFMA B-fragment layout (bf16) ----
__global__ void setup_kernel(unsigned short* __restrict__ ws,
                             const float* __restrict__ Wx, const float* __restrict__ Wh,
                             const float* __restrict__ Wp, const float* __restrict__ Wo) {
  int idx = blockIdx.x * 256 + threadIdx.x;
  if (idx < WS_BIG_SLOTS) {
    int lane = idx & 63, kt = (idx >> 6) & 3, ct = idx >> 8;
    int col = ct * 16 + (lane & 15);
    int k0 = kt * 32 + ((lane >> 4) << 3);
    unsigned short v[8];
#pragma unroll
    for (int j = 0; j < 8; ++j) {
      int k = k0 + j;
      float f = 0.f;
      if (k < 100) {
        if (col < 400) f = Wh[k * 400 + col];
        else if (col < 492) f = Wp[k * 92 + (col - 400)];
        else if (col < 500) f = Wo[k * 8 + (col - 492)];
      }
      v[j] = f2bf(f);
    }
    uint4 pk;
    pk.x = (unsigned)v[0] | ((unsigned)v[1] << 16);
    pk.y = (unsigned)v[2] | ((unsigned)v[3] << 16);
    pk.z = (unsigned)v[4] | ((unsigned)v[5] << 16);
    pk.w = (unsigned)v[6] | ((unsigned)v[7] << 16);
    *(uint4*)(ws + (size_t)idx * 8) = pk;
  } else if (idx < WS_BIG_SLOTS + WS_SM_SLOTS) {
    int s = idx - WS_BIG_SLOTS;
    int lane = s & 63, ct = s >> 6;
    int col = ct * 16 + (lane & 15);
    int k0 = (lane >> 4) << 3;
    unsigned short v[8];
#pragma unroll
    for (int j = 0; j < 8; ++j) {
      int k = k0 + j;
      float f = (k < 29) ? Wx[k * 400 + col] : 0.f;
      v[j] = f2bf(f);
    }
    uint4 pk;
    pk.x = (unsigned)v[0] | ((unsigned)v[1] << 16);
    pk.y = (unsigned)v[2] | ((unsigned)v[3] << 16);
    pk.z = (unsigned)v[4] | ((unsigned)v[5] << 16);
    pk.w = (unsigned)v[6] | ((unsigned)v[7] << 16);
    *(uint4*)(ws + (size_t)(WS_SM_OFF_U16 + (size_t)s * 8)) = pk;
  }
}

__global__ __launch_bounds__(NTHR, 4) void ntm_kernel(
    const float* __restrict__ inputs, const unsigned short* __restrict__ wsu,
    const float* __restrict__ b_lstm, const float* __restrict__ b_params,
    const float* __restrict__ b_out, const float* __restrict__ W_out,
    const int* __restrict__ seqp, float* __restrict__ outp) {
  extern __shared__ float sm[];
  const int tid = threadIdx.x;
  const int lane = tid & 63;
  const int wv = tid >> 6;
  const int b0 = blockIdx.x * G;
  const int tlim = seqp[0] + 1;
  const int TO = T_SEQ - tlim;
  const bool buffered = (TO <= 36);
  unsigned short* hAu = (unsigned short*)(sm + OFF_HA);
  unsigned short* sAu = (unsigned short*)(sm + OFF_SA);
  const bf16x8* wsBig = (const bf16x8*)wsu;
  const bf16x8* wsSm  = (const bf16x8*)(wsu + WS_SM_OFF_U16);

  // ---------------- init ----------------
  for (int i = tid; i < G * MSKT; i += NTHR) sm[OFF_M + i] = 1e-6f;
  for (int i = tid; i < 2048; i += NTHR) sm[OFF_GT + i] = 0.f;
  for (int i = tid; i < 400; i += NTHR) sm[OFF_C + i] = 0.f;
  for (int i = tid; i < HA_TOT; i += NTHR) hAu[i] = 0;
  for (int i = tid; i < SA_TOT; i += NTHR) sAu[i] = 0;
  if (tid < 512) {
    float v = 0.f;
    if (tid < 400) v = b_lstm[tid];
    else if (tid < 492) v = b_params[tid - 400];
    else if (tid < 500) v = b_out[tid - 492];
    sm[OFF_BIAS + tid] = v;
  }
  for (int i = tid; i < 80; i += NTHR) sm[OFF_R + i] = 0.f;
  for (int i = tid; i < 8 * W_ROW; i += NTHR)
    sm[OFF_W + i] = ((i % W_ROW) == 0) ? 1.f : 0.f;
  for (int i = tid; i < 160; i += NTHR) sm[OFF_WO2 + i] = W_out[800 + i];
  for (int i = tid; i < 1152; i += NTHR) sm[OFF_OUT + i] = 0.f;
  if (tid >= 448 && tid < 484) {  // x(0)
    int p = tid - 448, g = p / 9, k = p - g * 9;
    sAu[g * SA_STRIDE + k] = f2bf(inputs[(size_t)(b0 + g) * T_SEQ * IN_DIM + k]);
  }
  __syncthreads();

  const int arow = lane & 3;
  const int akoff = (lane >> 4) << 3;

  // ---- prologue: gates(0) = bias + [x(0), 0] @ Wx ----
  if (wv < 7) {
    bf16x8 as = *(const bf16x8*)(sAu + arow * SA_STRIDE + akoff);
#pragma unroll
    for (int cti = 0; cti < 4; ++cti) {
      int ct = wv * 4 + cti;
      if (ct < NCT_SM) {
        float bv = sm[OFF_BIAS + ct * 16 + (lane & 15)];
        f32x4 a = {bv, bv, bv, bv};
        a = __builtin_amdgcn_mfma_f32_16x16x32_bf16(as, wsSm[ct * 64 + lane], a, 0, 0, 0);
        if (lane < 16) *(f32x4*)&sm[OFF_GT + (ct * 16 + lane) * 4] = a;
      }
    }
  }
  __syncthreads();

  for (int t = 0; t < T_SEQ; ++t) {
    // ---- P_A: pointwise LSTM -> h hi/lo bf16 ; x prefetch ; output(t-1) ----
    if (tid < 400) {
      int e = tid >> 2, g = tid & 3;
      float gi = sm[OFF_GT + e * 4 + g];
      float gf = sm[OFF_GT + (100 + e) * 4 + g];
      float gz = sm[OFF_GT + (200 + e) * 4 + g];
      float go = sm[OFF_GT + (300 + e) * 4 + g];
      float c = sm[OFF_C + e * 4 + g];
      float nc = fsig(gf) * c + fsig(gi) * ftanh(gz);
      float h = fsig(go) * ftanh(nc);
      sm[OFF_C + e * 4 + g] = nc;
      unsigned short hh = f2bf(h);
      unsigned short hl = f2bf(h - bf2f(hh));
      hAu[g * HA_STRIDE + e] = hh;
      hAu[HA_LO + g * HA_STRIDE + e] = hl;
    } else if (tid >= 416 && tid < 452) {
      if (t + 1 < T_SEQ) {
        int p = tid - 416, g = p / 9, k = p - g * 9;
        sAu[g * SA_STRIDE + k] =
            f2bf(inputs[((size_t)(b0 + g) * T_SEQ + (t + 1)) * IN_DIM + k]);
      }
    } else if (tid >= 456 && tid < 488) {
      int s = t - 1;
      if (s >= tlim) {
        int u = tid - 456, g = u >> 3, o = u & 7;
        float v = sm[OFF_GT + (492 + o) * 4 + g];
#pragma unroll
        for (int d = 0; d < D; ++d)
          v = fmaf(sm[OFF_R + d * 4 + g], sm[OFF_WO2 + d * 8 + o], v);
        v = fminf(fmaxf(v, -CLIPV), CLIPV);
        v = fsig(v);
        int tp = s - tlim;
        if (buffered) sm[OFF_OUT + (g * TO + tp) * 8 + o] = v;
        else outp[((size_t)(b0 + g) * TO + tp) * 8 + o] = v;
      }
    }
    __syncthreads();  // B1

    // ---- P_B: p/hout tiles only (ct 25..31), one ct per wave ----
    if (wv < 7) {
      const int ct = 25 + wv;
      float bv = sm[OFF_BIAS + ct * 16 + (lane & 15)];
      f32x4 a = {bv, bv, bv, bv};
#pragma unroll
      for (int kt = 0; kt < 4; ++kt) {
        bf16x8 ahi = *(const bf16x8*)(hAu + arow * HA_STRIDE + kt * 32 + akoff);
        bf16x8 alo = *(const bf16x8*)(hAu + HA_LO + arow * HA_STRIDE + kt * 32 + akoff);
        bf16x8 bf = wsBig[(ct * 4 + kt) * 64 + lane];
        a = __builtin_amdgcn_mfma_f32_16x16x32_bf16(ahi, bf, a, 0, 0, 0);
        a = __builtin_amdgcn_mfma_f32_16x16x32_bf16(alo, bf, a, 0, 0, 0);
      }
      if (lane < 16) {
        int col = ct * 16 + lane;
        if (col < 492) {  // p: clip
          a.x = fminf(fmaxf(a.x, -CLIPV), CLIPV);
          a.y = fminf(fmaxf(a.y, -CLIPV), CLIPV);
          a.z = fminf(fmaxf(a.z, -CLIPV), CLIPV);
          a.w = fminf(fmaxf(a.w, -CLIPV), CLIPV);
        }
        *(f32x4*)&sm[OFF_GT + col * 4] = a;
      }
    }
    __syncthreads();  // B2

    // ---- P_C: waves 0-3 dual-head addressing ; waves 4-7 gates GEMM (overlap) ----
    if (wv < 4) {
      const int g = wv, l = lane;
      if (l < 40) {
        int hd = l >= 20, j = l - 20 * hd;
        sm[OFF_KV + (2 * g + hd) * 20 + j] =
            ftanh(sm[OFF_GT + (400 + hd * 26 + j) * 4 + g]);
      } else if (l < 52) {
        int hd = (l - 40) >= 6, which = (l - 40) - 6 * hd;
        float v = sm[OFF_GT + (400 + hd * 26 + 20 + which) * 4 + g];
        float* scp = &sm[OFF_SC + (2 * g + hd) * 8];
        if (which == 0) scp[0] = fsoftplus(v);
        else if (which == 1) scp[1] = fsig(v);
        else if (which == 2) {
          float a1 = sm[OFF_GT + (400 + hd * 26 + 23) * 4 + g];
          float a2 = sm[OFF_GT + (400 + hd * 26 + 24) * 4 + g];
          float mx = fmaxf(v, fmaxf(a1, a2));
          float e0 = fexp(v - mx), e1 = fexp(a1 - mx), e2 = fexp(a2 - mx);
          float inv = frcp(e0 + e1 + e2);
          scp[2] = e0 * inv; scp[3] = e1 * inv; scp[4] = e2 * inv;
        } else if (which == 5) {
          scp[5] = fsoftplus(v) + 1.f;
        }
      }
      asm volatile("s_waitcnt lgkmcnt(0)" ::: "memory");
      __builtin_amdgcn_sched_barrier(0);

      const float* Mg = &sm[OFF_M + g * MSKT];
      const float* kv0 = &sm[OFF_KV + (2 * g) * 20];
      const float* kv1 = &sm[OFF_KV + (2 * g + 1) * 20];
      float d00 = 0.f, d01 = 0.f, d10 = 0.f, d11 = 0.f;
      float kn0 = 0.f, kn1 = 0.f, n0s = 0.f, n1s = 0.f;
#pragma unroll
      for (int d = 0; d < D; ++d) {
        float k0 = kv0[d], k1 = kv1[d];
        float m0 = Mg[d * MT_ROW + l], m1 = Mg[d * MT_ROW + 64 + l];
        d00 = fmaf(k0, m0, d00); d01 = fmaf(k0, m1, d01);
        d10 = fmaf(k1, m0, d10); d11 = fmaf(k1, m1, d11);
        kn0 = fmaf(k0, k0, kn0); kn1 = fmaf(k1, k1, kn1);
        n0s = fmaf(m0, m0, n0s); n1s = fmaf(m1, m1, n1s);
      }
      kn0 = sqrtf(kn0); kn1 = sqrtf(kn1);
      float Mn0 = sqrtf(n0s), Mn1 = sqrtf(n1s);
      const float* sc0 = &sm[OFF_SC + (2 * g) * 8];
      const float* sc1 = &sm[OFF_SC + (2 * g + 1) * 8];
      float be0 = sc0[0], be1 = sc1[0];
      float S00 = be0 * d00 * frcp(kn0 * Mn0 + 1e-8f);
      float S01 = be0 * d01 * frcp(kn0 * Mn1 + 1e-8f);
      float S10 = be1 * d10 * frcp(kn1 * Mn0 + 1e-8f);
      float S11 = be1 * d11 * frcp(kn1 * Mn1 + 1e-8f);
      float mx0 = fmaxf(S00, S01), mx1 = fmaxf(S10, S11);
      wred_max2(mx0, mx1);
      float e00 = fexp(S00 - mx0), e01 = fexp(S01 - mx0);
      float e10 = fexp(S10 - mx1), e11 = fexp(S11 - mx1);
      float sum0 = e00 + e01, sum1 = e10 + e11;
      wred_sum2(sum0, sum1);
      float si0 = frcp(sum0), si1 = frcp(sum1);
      float* wpa = &sm[OFF_W + (2 * g) * W_ROW];
      float* wpb = &sm[OFF_W + (2 * g + 1) * W_ROW];
      float gg0 = sc0[1], gg1 = sc1[1];
      float wa0 = wpa[l], wa1 = wpa[64 + l], wb0 = wpb[l], wb1 = wpb[64 + l];
      float wg00 = fmaf(gg0, e00 * si0 - wa0, wa0);
      float wg01 = fmaf(gg0, e01 * si0 - wa1, wa1);
      float wg10 = fmaf(gg1, e10 * si1 - wb0, wb0);
      float wg11 = fmaf(gg1, e11 * si1 - wb1, wb1);
      int lp = (l + 1) & 63, lm = (l + 63) & 63;
      float n00 = __shfl(wg00, lp, 64), n01 = __shfl(wg01, lp, 64);
      float p00 = __shfl(wg00, lm, 64), p01 = __shfl(wg01, lm, 64);
      float a0l0 = __shfl(wg00, 0, 64), a1l0 = __shfl(wg01, 0, 64);
      float a0l63 = __shfl(wg00, 63, 64), a1l63 = __shfl(wg01, 63, 64);
      float nxt00 = (l == 63) ? a1l0 : n00;
      float nxt01 = (l == 63) ? a0l0 : n01;
      float prv00 = (l == 0) ? a1l63 : p00;
      float prv01 = (l == 0) ? a0l63 : p01;
      float n10 = __shfl(wg10, lp, 64), n11 = __shfl(wg11, lp, 64);
      float p10 = __shfl(wg10, lm, 64), p11 = __shfl(wg11, lm, 64);
      float b0l0 = __shfl(wg10, 0, 64), b1l0 = __shfl(wg11, 0, 64);
      float b0l63 = __shfl(wg10, 63, 64), b1l63 = __shfl(wg11, 63, 64);
      float nxt10 = (l == 63) ? b1l0 : n10;
      float nxt11 = (l == 63) ? b0l0 : n11;
      float prv10 = (l == 0) ? b1l63 : p10;
      float prv11 = (l == 0) ? b0l63 : p11;
      float s00 = sc0[2], s01s = sc0[3], s02 = sc0[4], gm0 = sc0[5];
      float s10 = sc1[2], s11s = sc1[3], s12 = sc1[4], gm1 = sc1[5];
      float wt00 = fmaxf(fmaf(s00, nxt00, fmaf(s01s, wg00, s02 * prv00)), 1e-16f);
      float wt01 = fmaxf(fmaf(s00, nxt01, fmaf(s01s, wg01, s02 * prv01)), 1e-16f);
      float wt10 = fmaxf(fmaf(s10, nxt10, fmaf(s11s, wg10, s12 * prv10)), 1e-16f);
      float wt11 = fmaxf(fmaf(s10, nxt11, fmaf(s11s, wg11, s12 * prv11)), 1e-16f);
      float m0m = fmaxf(wt00, wt01), m1m = fmaxf(wt10, wt11);
      wred_max2(m0m, m1m);
      float iv0 = frcp(m0m), iv1 = frcp(m1m);
      float q00 = fexp2(gm0 * flog2(wt00 * iv0));
      float q01 = fexp2(gm0 * flog2(wt01 * iv0));
      float q10 = fexp2(gm1 * flog2(wt10 * iv1));
      float q11 = fexp2(gm1 * flog2(wt11 * iv1));
      float sq0 = q00 + q01, sq1 = q10 + q11;
      wred_sum2(sq0, sq1);
      float pi0 = frcp(sq0), pi1 = frcp(sq1);
      wpa[l] = q00 * pi0; wpa[64 + l] = q01 * pi0;
      wpb[l] = q10 * pi1; wpb[64 + l] = q11 * pi1;
    } else {
      // gates GEMM for t+1 partial: 25 tiles strided over waves 4-7
      const int wq = wv - 4;
      bf16x8 ahi[4], alo[4];
#pragma unroll
      for (int kt = 0; kt < 4; ++kt) {
        ahi[kt] = *(const bf16x8*)(hAu + arow * HA_STRIDE + kt * 32 + akoff);
        alo[kt] = *(const bf16x8*)(hAu + HA_LO + arow * HA_STRIDE + kt * 32 + akoff);
      }
#pragma unroll
      for (int cti = 0; cti < 7; ++cti) {
        int ct = wq + cti * 4;
        if (ct < NCT_SM) {
          float bv = sm[OFF_BIAS + ct * 16 + (lane & 15)];
          f32x4 a = {bv, bv, bv, bv};
#pragma unroll
          for (int kt = 0; kt < 4; ++kt) {
            bf16x8 bf = wsBig[(ct * 4 + kt) * 64 + lane];
            a = __builtin_amdgcn_mfma_f32_16x16x32_bf16(ahi[kt], bf, a, 0, 0, 0);
            a = __builtin_amdgcn_mfma_f32_16x16x32_bf16(alo[kt], bf, a, 0, 0, 0);
          }
          if (lane < 16) *(f32x4*)&sm[OFF_GT + (ct * 16 + lane) * 4] = a;
        }
      }
    }
    __syncthreads();  // B3

    // ---- P_D: r = w_r @ M (float4) ; e/a activations ----
    if (tid < 320) {
      int pr = tid >> 2, nq = tid & 3;
      int g = pr / 20, d = pr - g * 20;
      const float* wr = &sm[OFF_W + (2 * g) * W_ROW];
      const float* Md = &sm[OFF_M + g * MSKT + d * MT_ROW];
      float s = 0.f;
#pragma unroll
      for (int i = 0; i < 8; ++i) {
        int n = nq * 4 + i * 16;
        float4 w4 = *(const float4*)(wr + n);
        float4 m4 = *(const float4*)(Md + n);
        s = fmaf(w4.x, m4.x, fmaf(w4.y, m4.y, fmaf(w4.z, m4.z, fmaf(w4.w, m4.w, s))));
      }
      s = qred(s);
      if (nq == 0) {
        sm[OFF_R + d * 4 + g] = s;
        sAu[g * SA_STRIDE + 9 + d] = f2bf(s);
      }
    } else if (tid < 480) {
      int p = tid - 320, g = p / 40, j = p - g * 40;
      float v = sm[OFF_GT + (452 + j) * 4 + g];
      sm[OFF_EA + g * 40 + j] = (j < 20) ? fsig(v) : ftanh(v);
    }
    __syncthreads();  // B4

    // ---- P_E: small GEMM += gates partial (C from LDS) ; M update ----
    if (wv < 7) {
      bf16x8 as = *(const bf16x8*)(sAu + arow * SA_STRIDE + akoff);
#pragma unroll
      for (int cti = 0; cti < 4; ++cti) {
        int ct = wv * 4 + cti;
        if (ct < NCT_SM) {
          bf16x8 bs = wsSm[ct * 64 + lane];
          f32x4 c = *(const f32x4*)&sm[OFF_GT + (ct * 16 + (lane & 15)) * 4];
          c = __builtin_amdgcn_mfma_f32_16x16x32_bf16(as, bs, c, 0, 0, 0);
          if (lane < 16) *(f32x4*)&sm[OFF_GT + (ct * 16 + lane) * 4] = c;
        }
      }
    }
    if (tid < 256) {
      int g = tid >> 6, n0 = tid & 63;
      const float* ep = &sm[OFF_EA + g * 40];
      const float* ap = ep + 20;
      float* Mg = &sm[OFF_M + g * MSKT];
#pragma unroll
      for (int h2 = 0; h2 < 2; ++h2) {
        int n = n0 + 64 * h2;
        float ww = sm[OFF_W + (2 * g + 1) * W_ROW + n];
#pragma unroll
        for (int d = 0; d < D; ++d) {
          float mv = Mg[d * MT_ROW + n];
          Mg[d * MT_ROW + n] = fmaf(ww, fmaf(-ep[d], mv, ap[d]), mv);
        }
      }
    }
    __syncthreads();  // B5
  }

  // ---- epilogue: output for t = T_SEQ-1, then flush ----
  if (tid < 32) {
    int s = T_SEQ - 1;
    if (s >= tlim) {
      int g = tid >> 3, o = tid & 7;
      float v = sm[OFF_GT + (492 + o) * 4 + g];
#pragma unroll
      for (int d = 0; d < D; ++d)
        v = fmaf(sm[OFF_R + d * 4 + g], sm[OFF_WO2 + d * 8 + o], v);
      v = fminf(fmaxf(v, -CLIPV), CLIPV);
      v = fsig(v);
      int tp = s - tlim;
      if (buffered) sm[OFF_OUT + (g * TO + tp) * 8 + o] = v;
      else outp[((size_t)(b0 + g) * TO + tp) * 8 + o] = v;
    }
  }
  __syncthreads();
  if (buffered) {
    const int total = G * TO * 8;
    for (int i = tid * 4; i < total; i += NTHR * 4) {
      float4 v = *(const float4*)&sm[OFF_OUT + i];
      *(float4*)&outp[(size_t)blockIdx.x * total + i] = v;
    }
  }
}

}  // namespace

extern "C" void kernel_launch(void* const* d_in, const int* in_sizes, int n_in,
                              void* d_out, int out_size, void* d_ws, size_t ws_size,
                              hipStream_t stream) {
  (void)in_sizes; (void)n_in; (void)out_size; (void)ws_size;
  const float* inputs   = (const float*)d_in[0];
  const float* Wx       = (const float*)d_in[1];
  const float* Wh       = (const float*)d_in[2];
  const float* b_lstm   = (const float*)d_in[3];
  const float* W_params = (const float*)d_in[4];
  const float* b_params = (const float*)d_in[5];
  const float* W_out    = (const float*)d_in[6];
  const float* b_out    = (const float*)d_in[7];
  const int*   seqp     = (const int*)d_in[8];
  float* out = (float*)d_out;
  unsigned short* wsu = (unsigned short*)d_ws;

  constexpr int SETUP_N = WS_BIG_SLOTS + WS_SM_SLOTS;  // 9792
  setup_kernel<<<(SETUP_N + 255) / 256, 256, 0, stream>>>(wsu, Wx, Wh, W_params,
                                                          W_out);

  hipFuncSetAttribute((const void*)ntm_kernel,
                      hipFuncAttributeMaxDynamicSharedMemorySize, SMEM_BYTES);
  ntm_kernel<<<B_TOT / G, NTHR, SMEM_BYTES, stream>>>(
      inputs, wsu, b_lstm, b_params, b_out, W_out, seqp, out);
}